// Round 6
// baseline (308.486 us; speedup 1.0000x reference)
//
#include <hip/hip_runtime.h>
#include <math.h>

typedef float fx4 __attribute__((ext_vector_type(4)));

#define GRID 2048

__device__ inline float nsq(float s2) {
    // sum(normalize(x)^2) = s2 / max(sqrt(s2), eps)^2  (F.normalize semantics)
    const float eps = 1e-12f;
    float m = fmaxf(sqrtf(s2), eps);
    return s2 / (m * m);
}

// R5 hot loop (unchanged) + last-block-done finalize (no second dispatch).
// 2048 blocks x 256 threads = 8192 waves, each wave owns 2 contiguous rows.
__global__ __launch_bounds__(256) void fused_kernel(
    const float* __restrict__ m0, const float* __restrict__ m1,
    const float* __restrict__ m2, const float* __restrict__ m3,
    float* __restrict__ row_ss /* [16384] */,
    unsigned int* __restrict__ counter,
    float* __restrict__ out) {
    const int wid  = (blockIdx.x << 2) | (threadIdx.x >> 6);  // 0..8191
    const int lane = threadIdx.x & 63;
    const int r0   = wid << 1;          // first flat row; both rows same matrix
    const int mat  = r0 >> 12;
    const int row  = r0 & 4095;
    const float* in = (mat == 0) ? m0 : (mat == 1) ? m1 : (mat == 2) ? m2 : m3;

    const fx4* p = reinterpret_cast<const fx4*>(in + (size_t)row * 4096) + lane;

#pragma unroll
    for (int rr = 0; rr < 2; ++rr) {
        const fx4* q = p + rr * 1024;
        float c0 = 0.f, c1 = 0.f, c2 = 0.f, c3 = 0.f;
#pragma unroll
        for (int k = 0; k < 4; ++k) {
            fx4 v0 = q[(k * 4 + 0) * 64];
            fx4 v1 = q[(k * 4 + 1) * 64];
            fx4 v2 = q[(k * 4 + 2) * 64];
            fx4 v3 = q[(k * 4 + 3) * 64];
            c0 += v0.x * v0.x + v0.y * v0.y + v0.z * v0.z + v0.w * v0.w;
            c1 += v1.x * v1.x + v1.y * v1.y + v1.z * v1.z + v1.w * v1.w;
            c2 += v2.x * v2.x + v2.y * v2.y + v2.z * v2.z + v2.w * v2.w;
            c3 += v3.x * v3.x + v3.y * v3.y + v3.z * v3.z + v3.w * v3.w;
        }
        float acc = (c0 + c1) + (c2 + c3);
#pragma unroll
        for (int off = 32; off > 0; off >>= 1) acc += __shfl_down(acc, off);
        if (lane == 0) row_ss[r0 + rr] = acc;
    }

    // ---- last-block-done finalize (writer-side release, reader-side acquire) ----
    __threadfence();                     // each writer pushes its row_ss store device-scope
    __syncthreads();
    __shared__ unsigned int ticket;
    if (threadIdx.x == 0) ticket = atomicAdd(counter, 1u);
    __syncthreads();
    if (ticket != GRID - 1) return;

    __threadfence();                     // acquire: see all blocks' row_ss
    const fx4* r2  = reinterpret_cast<const fx4*>(row_ss);          // rna
    const fx4* w2  = reinterpret_cast<const fx4*>(row_ss + 4096);   // wsi
    const fx4* rw2 = reinterpret_cast<const fx4*>(row_ss + 8192);   // rna_wsi
    const fx4* wr2 = reinterpret_cast<const fx4*>(row_ss + 12288);  // wsi_rna

    float sum_d1 = 0.0f, sum_d2 = 0.0f;
    for (int i = threadIdx.x; i < 1024; i += 256) {
        fx4 a = r2[i], b = w2[i], c = rw2[i], d = wr2[i];
#pragma unroll
        for (int j = 0; j < 4; ++j) {
            sum_d1 += nsq(a[j]) * nsq(b[j]);                 // D1
            sum_d2 += nsq(d[j] + c[j]) * nsq(a[j] + b[j]);   // D2 (concat norms add)
        }
    }
#pragma unroll
    for (int off = 32; off > 0; off >>= 1) {
        sum_d1 += __shfl_down(sum_d1, off);
        sum_d2 += __shfl_down(sum_d2, off);
    }
    __shared__ float s1[4], s2[4];
    if ((threadIdx.x & 63) == 0) {
        s1[threadIdx.x >> 6] = sum_d1;
        s2[threadIdx.x >> 6] = sum_d2;
    }
    __syncthreads();
    if (threadIdx.x == 0) {
        float d1 = ((s1[0] + s1[1]) + (s1[2] + s1[3])) * (1.0f / 4096.0f);
        float d2 = ((s2[0] + s2[1]) + (s2[2] + s2[3])) * (1.0f / 4096.0f);
        out[0] = 0.5f * d2 + 0.5f * d1;  // loss
        out[1] = d1;                     // loss_D1
        out[2] = d2;                     // loss_D2
    }
}

extern "C" void kernel_launch(void* const* d_in, const int* in_sizes, int n_in,
                              void* d_out, int out_size, void* d_ws, size_t ws_size,
                              hipStream_t stream) {
    const float* rna    = (const float*)d_in[0];
    const float* wsi    = (const float*)d_in[1];
    const float* rnawsi = (const float*)d_in[2];
    const float* wsirna = (const float*)d_in[3];
    float* out = (float*)d_out;
    float* row_ss = (float*)d_ws;                                   // 16384 floats
    unsigned int* counter = (unsigned int*)((char*)d_ws + 16384 * sizeof(float));

    hipMemsetAsync(counter, 0, sizeof(unsigned int), stream);       // graph-capture legal
    fused_kernel<<<GRID, 256, 0, stream>>>(rna, wsi, rnawsi, wsirna, row_ss, counter, out);
}

// Round 7
// 49.746 us; speedup vs baseline: 6.2013x; 6.2013x over previous
//
#include <hip/hip_runtime.h>
#include <math.h>

typedef float fx4 __attribute__((ext_vector_type(4)));

// 2048 blocks x 256 threads = 8192 waves; each wave owns 2 contiguous rows
// (32 KB contiguous stream). Both rows' accumulators are built first, then
// the two 6-step shuffle-reduce chains run interleaved (ILP hides shuffle
// latency). No LDS, no __syncthreads in the hot kernel.
__global__ __launch_bounds__(256) void rowsumsq_kernel(
    const float* __restrict__ m0, const float* __restrict__ m1,
    const float* __restrict__ m2, const float* __restrict__ m3,
    float* __restrict__ row_ss /* [16384] */) {
    const int wid  = (blockIdx.x << 2) | (threadIdx.x >> 6);  // 0..8191
    const int lane = threadIdx.x & 63;
    const int r0   = wid << 1;          // first flat row; both rows same matrix
    const int mat  = r0 >> 12;
    const int row  = r0 & 4095;
    const float* in = (mat == 0) ? m0 : (mat == 1) ? m1 : (mat == 2) ? m2 : m3;

    const fx4* p = reinterpret_cast<const fx4*>(in + (size_t)row * 4096) + lane;

    float acc[2];
#pragma unroll
    for (int rr = 0; rr < 2; ++rr) {
        const fx4* q = p + rr * 1024;
        float c0 = 0.f, c1 = 0.f, c2 = 0.f, c3 = 0.f;
#pragma unroll
        for (int k = 0; k < 4; ++k) {
            fx4 v0 = q[(k * 4 + 0) * 64];
            fx4 v1 = q[(k * 4 + 1) * 64];
            fx4 v2 = q[(k * 4 + 2) * 64];
            fx4 v3 = q[(k * 4 + 3) * 64];
            c0 += v0.x * v0.x + v0.y * v0.y + v0.z * v0.z + v0.w * v0.w;
            c1 += v1.x * v1.x + v1.y * v1.y + v1.z * v1.z + v1.w * v1.w;
            c2 += v2.x * v2.x + v2.y * v2.y + v2.z * v2.z + v2.w * v2.w;
            c3 += v3.x * v3.x + v3.y * v3.y + v3.z * v3.z + v3.w * v3.w;
        }
        acc[rr] = (c0 + c1) + (c2 + c3);
    }

    // Interleaved dual reduce: the two dependency chains overlap.
    float a0 = acc[0], a1 = acc[1];
#pragma unroll
    for (int off = 32; off > 0; off >>= 1) {
        a0 += __shfl_down(a0, off);
        a1 += __shfl_down(a1, off);
    }
    if (lane == 0) {
        row_ss[r0]     = a0;
        row_ss[r0 + 1] = a1;
    }
}

__device__ inline float nsq(float s2) {
    // sum(normalize(x)^2) = s2 / max(sqrt(s2), eps)^2  (F.normalize semantics)
    const float eps = 1e-12f;
    float m = fmaxf(sqrtf(s2), eps);
    return s2 / (m * m);
}

// Single block, 1024 threads: combine 4*4096 row sums into the 3 scalars.
// Each thread handles exactly 4 rows (one fx4 column slice per matrix).
__global__ __launch_bounds__(1024) void finalize_kernel(
    const float* __restrict__ row_ss, float* __restrict__ out) {
    const fx4* r2  = reinterpret_cast<const fx4*>(row_ss);          // rna
    const fx4* w2  = reinterpret_cast<const fx4*>(row_ss + 4096);   // wsi
    const fx4* rw2 = reinterpret_cast<const fx4*>(row_ss + 8192);   // rna_wsi
    const fx4* wr2 = reinterpret_cast<const fx4*>(row_ss + 12288);  // wsi_rna

    const int i = threadIdx.x;   // 0..1023, covers 4096 rows as fx4
    fx4 a = r2[i], b = w2[i], c = rw2[i], d = wr2[i];
    float sum_d1 = 0.0f, sum_d2 = 0.0f;
#pragma unroll
    for (int j = 0; j < 4; ++j) {
        sum_d1 += nsq(a[j]) * nsq(b[j]);                 // D1
        sum_d2 += nsq(d[j] + c[j]) * nsq(a[j] + b[j]);   // D2 (concat norms add)
    }

#pragma unroll
    for (int off = 32; off > 0; off >>= 1) {
        sum_d1 += __shfl_down(sum_d1, off);
        sum_d2 += __shfl_down(sum_d2, off);
    }
    __shared__ float s1[16], s2[16];
    if ((threadIdx.x & 63) == 0) {
        s1[threadIdx.x >> 6] = sum_d1;
        s2[threadIdx.x >> 6] = sum_d2;
    }
    __syncthreads();
    if (threadIdx.x == 0) {
        float d1 = 0.f, d2 = 0.f;
#pragma unroll
        for (int k = 0; k < 16; ++k) { d1 += s1[k]; d2 += s2[k]; }
        d1 *= (1.0f / 4096.0f);
        d2 *= (1.0f / 4096.0f);
        out[0] = 0.5f * d2 + 0.5f * d1;  // loss
        out[1] = d1;                     // loss_D1
        out[2] = d2;                     // loss_D2
    }
}

extern "C" void kernel_launch(void* const* d_in, const int* in_sizes, int n_in,
                              void* d_out, int out_size, void* d_ws, size_t ws_size,
                              hipStream_t stream) {
    const float* rna    = (const float*)d_in[0];
    const float* wsi    = (const float*)d_in[1];
    const float* rnawsi = (const float*)d_in[2];
    const float* wsirna = (const float*)d_in[3];
    float* out = (float*)d_out;
    float* row_ss = (float*)d_ws;  // 16384 floats = 64 KB

    rowsumsq_kernel<<<2048, 256, 0, stream>>>(rna, wsi, rnawsi, wsirna, row_ss);
    finalize_kernel<<<1, 1024, 0, stream>>>(row_ss, out);
}

// Round 8
// 47.378 us; speedup vs baseline: 6.5112x; 1.0500x over previous
//
#include <hip/hip_runtime.h>
#include <math.h>

typedef float fx4 __attribute__((ext_vector_type(4)));

// R5 hot kernel (best: 48.0 us, VGPR=32, occ ~54%): 2048 blocks x 256 threads
// = 8192 waves; each wave owns 2 contiguous rows (32 KB contiguous stream),
// reducing each row immediately (short VGPR live ranges -> high occupancy).
// No LDS, no __syncthreads in the hot kernel.
__global__ __launch_bounds__(256) void rowsumsq_kernel(
    const float* __restrict__ m0, const float* __restrict__ m1,
    const float* __restrict__ m2, const float* __restrict__ m3,
    float* __restrict__ row_ss /* [16384] */) {
    const int wid  = (blockIdx.x << 2) | (threadIdx.x >> 6);  // 0..8191
    const int lane = threadIdx.x & 63;
    const int r0   = wid << 1;          // first flat row; both rows same matrix
    const int mat  = r0 >> 12;
    const int row  = r0 & 4095;
    const float* in = (mat == 0) ? m0 : (mat == 1) ? m1 : (mat == 2) ? m2 : m3;

    const fx4* p = reinterpret_cast<const fx4*>(in + (size_t)row * 4096) + lane;

#pragma unroll
    for (int rr = 0; rr < 2; ++rr) {
        const fx4* q = p + rr * 1024;
        float c0 = 0.f, c1 = 0.f, c2 = 0.f, c3 = 0.f;
#pragma unroll
        for (int k = 0; k < 4; ++k) {
            fx4 v0 = q[(k * 4 + 0) * 64];
            fx4 v1 = q[(k * 4 + 1) * 64];
            fx4 v2 = q[(k * 4 + 2) * 64];
            fx4 v3 = q[(k * 4 + 3) * 64];
            c0 += v0.x * v0.x + v0.y * v0.y + v0.z * v0.z + v0.w * v0.w;
            c1 += v1.x * v1.x + v1.y * v1.y + v1.z * v1.z + v1.w * v1.w;
            c2 += v2.x * v2.x + v2.y * v2.y + v2.z * v2.z + v2.w * v2.w;
            c3 += v3.x * v3.x + v3.y * v3.y + v3.z * v3.z + v3.w * v3.w;
        }
        float acc = (c0 + c1) + (c2 + c3);
#pragma unroll
        for (int off = 32; off > 0; off >>= 1) acc += __shfl_down(acc, off);
        if (lane == 0) row_ss[r0 + rr] = acc;
    }
}

__device__ inline float nsq(float s2) {
    // sum(normalize(x)^2) = s2 / max(sqrt(s2), eps)^2  (F.normalize semantics)
    const float eps = 1e-12f;
    float m = fmaxf(sqrtf(s2), eps);
    return s2 / (m * m);
}

// Single block, 1024 threads: combine 4*4096 row sums into the 3 scalars.
// Each thread handles exactly one fx4 slice per matrix (no loop).
__global__ __launch_bounds__(1024) void finalize_kernel(
    const float* __restrict__ row_ss, float* __restrict__ out) {
    const fx4* r2  = reinterpret_cast<const fx4*>(row_ss);          // rna
    const fx4* w2  = reinterpret_cast<const fx4*>(row_ss + 4096);   // wsi
    const fx4* rw2 = reinterpret_cast<const fx4*>(row_ss + 8192);   // rna_wsi
    const fx4* wr2 = reinterpret_cast<const fx4*>(row_ss + 12288);  // wsi_rna

    const int i = threadIdx.x;   // 0..1023 covers 4096 rows as fx4
    fx4 a = r2[i], b = w2[i], c = rw2[i], d = wr2[i];
    float sum_d1 = 0.0f, sum_d2 = 0.0f;
#pragma unroll
    for (int j = 0; j < 4; ++j) {
        sum_d1 += nsq(a[j]) * nsq(b[j]);                 // D1
        sum_d2 += nsq(d[j] + c[j]) * nsq(a[j] + b[j]);   // D2 (concat norms add)
    }

#pragma unroll
    for (int off = 32; off > 0; off >>= 1) {
        sum_d1 += __shfl_down(sum_d1, off);
        sum_d2 += __shfl_down(sum_d2, off);
    }
    __shared__ float s1[16], s2[16];
    if ((threadIdx.x & 63) == 0) {
        s1[threadIdx.x >> 6] = sum_d1;
        s2[threadIdx.x >> 6] = sum_d2;
    }
    __syncthreads();
    if (threadIdx.x == 0) {
        float d1 = 0.f, d2 = 0.f;
#pragma unroll
        for (int k = 0; k < 16; ++k) { d1 += s1[k]; d2 += s2[k]; }
        d1 *= (1.0f / 4096.0f);
        d2 *= (1.0f / 4096.0f);
        out[0] = 0.5f * d2 + 0.5f * d1;  // loss
        out[1] = d1;                     // loss_D1
        out[2] = d2;                     // loss_D2
    }
}

extern "C" void kernel_launch(void* const* d_in, const int* in_sizes, int n_in,
                              void* d_out, int out_size, void* d_ws, size_t ws_size,
                              hipStream_t stream) {
    const float* rna    = (const float*)d_in[0];
    const float* wsi    = (const float*)d_in[1];
    const float* rnawsi = (const float*)d_in[2];
    const float* wsirna = (const float*)d_in[3];
    float* out = (float*)d_out;
    float* row_ss = (float*)d_ws;  // 16384 floats = 64 KB

    rowsumsq_kernel<<<2048, 256, 0, stream>>>(rna, wsi, rnawsi, wsirna, row_ss);
    finalize_kernel<<<1, 1024, 0, stream>>>(row_ss, out);
}